// Round 1
// baseline (34.856 us; speedup 1.0000x reference)
//
#include <hip/hip_runtime.h>

#define NEG_INF_F (-10000.0f)
#define EPS_F (1e-8f)

// ---------------------------------------------------------------------------
// Kernel A: per-row reductions. One 64-lane wave per (b,s) row.
//   d1[b,s] = row . q1(b)     (q1 = seq[b,1,:])
//   d2[b,s] = row . q2(b)     (q2 = seq[b,sep0-1,:])
//   n2[b,s] = row . row
// float4 loads: 16 B/lane * 64 lanes = 1 KiB per instruction, 4 iters for H=1024.
// ---------------------------------------------------------------------------
__global__ __launch_bounds__(256) void row_stats_kernel(
    const float* __restrict__ seq, const int* __restrict__ idxs,
    float* __restrict__ d1, float* __restrict__ d2, float* __restrict__ n2,
    int B, int S, int H) {
  int gtid = blockIdx.x * blockDim.x + threadIdx.x;
  int row = gtid >> 6;          // one wave per row
  int lane = threadIdx.x & 63;
  int nrows = B * S;
  if (row >= nrows) return;

  int b = row / S;
  int sep0 = idxs[b * 2 + 0];

  const float* rowp = seq + (size_t)row * H;
  const float* q1p = seq + ((size_t)b * S + 1) * H;
  const float* q2p = seq + ((size_t)b * S + (sep0 - 1)) * H;

  float s1 = 0.f, s2 = 0.f, sn = 0.f;
  for (int h = lane * 4; h < H; h += 64 * 4) {
    float4 x = *reinterpret_cast<const float4*>(rowp + h);
    float4 a = *reinterpret_cast<const float4*>(q1p + h);
    float4 c = *reinterpret_cast<const float4*>(q2p + h);
    s1 += x.x * a.x + x.y * a.y + x.z * a.z + x.w * a.w;
    s2 += x.x * c.x + x.y * c.y + x.z * c.z + x.w * c.w;
    sn += x.x * x.x + x.y * x.y + x.z * x.z + x.w * x.w;
  }
  // 64-lane butterfly reduction, no LDS needed.
  #pragma unroll
  for (int off = 32; off >= 1; off >>= 1) {
    s1 += __shfl_xor(s1, off, 64);
    s2 += __shfl_xor(s2, off, 64);
    sn += __shfl_xor(sn, off, 64);
  }
  if (lane == 0) {
    d1[row] = s1;
    d2[row] = s2;
    n2[row] = sn;
  }
}

// ---------------------------------------------------------------------------
// Kernel B: windowed max over L offsets. One thread per (b,s).
// Stats arrays (3 * 128 KiB) are L2-resident; the L-wide window walk hits L1.
// First-occurrence argmax via strict '>' (matches jnp.argmax tie-breaking).
// ---------------------------------------------------------------------------
__global__ __launch_bounds__(256) void window_max_kernel(
    const float* __restrict__ d1, const float* __restrict__ d2,
    const float* __restrict__ n2, const int* __restrict__ idxs,
    const int* __restrict__ pL,
    float* __restrict__ out, int B, int S) {
  int t = blockIdx.x * blockDim.x + threadIdx.x;
  int nrows = B * S;
  if (t >= nrows) return;
  int b = t / S;
  int s = t - b * S;

  int sep0 = idxs[b * 2 + 0];
  int sep1 = idxs[b * 2 + 1];
  int L = pL[0];

  // qn2 = ||q1||^2 + ||q2||^2 ; both already available as n2 entries.
  float qn2 = n2[(size_t)b * S + 1] + n2[(size_t)b * S + (sep0 - 1)];
  float my_d1 = d1[t];
  float my_n2 = n2[t];

  float best = NEG_INF_F;
  int best_l = 0;
  const float* d2b = d2 + (size_t)b * S;
  const float* n2b = n2 + (size_t)b * S;
  for (int l = 0; l < L; ++l) {
    float sim;
    if (s + l < sep1) {
      int j = min(s + l, S - 1);
      float denom = fmaxf(sqrtf((my_n2 + n2b[j]) * qn2), EPS_F);
      sim = (my_d1 + d2b[j]) / denom;
    } else {
      sim = NEG_INF_F;
    }
    if (sim > best) { best = sim; best_l = l; }
  }

  bool valid_i = (s > sep0) && (s < sep1);
  out[t] = valid_i ? best : NEG_INF_F;                        // max_vals
  out[nrows + t] = valid_i ? (float)(s + best_l) : -1.0f;     // end_idx as f32
}

extern "C" void kernel_launch(void* const* d_in, const int* in_sizes, int n_in,
                              void* d_out, int out_size, void* d_ws, size_t ws_size,
                              hipStream_t stream) {
  const float* seq = (const float*)d_in[0];
  const int* idxs = (const int*)d_in[1];
  const int* pL = (const int*)d_in[2];

  // Derive shapes: in_sizes[1] = B*2, out_size = 2*B*S, in_sizes[0] = B*S*H.
  int B = in_sizes[1] / 2;
  int S = out_size / (2 * B);
  int H = (int)((long long)in_sizes[0] / ((long long)B * S));
  int nrows = B * S;

  float* d1 = (float*)d_ws;
  float* d2 = d1 + nrows;
  float* n2 = d2 + nrows;

  // Kernel A: one wave per row, 4 waves per block.
  int rows_per_block = 4;
  int gridA = (nrows + rows_per_block - 1) / rows_per_block;
  row_stats_kernel<<<gridA, 256, 0, stream>>>(seq, idxs, d1, d2, n2, B, S, H);

  // Kernel B: one thread per row.
  int gridB = (nrows + 255) / 256;
  window_max_kernel<<<gridB, 256, 0, stream>>>(d1, d2, n2, idxs, pL,
                                               (float*)d_out, B, S);
}